// Round 1
// baseline (5751.251 us; speedup 1.0000x reference)
//
#include <hip/hip_runtime.h>
#include <math.h>

// ODE-RNN forward: B=512, K=1024, U=16, P=32, H=128, L=32, TD=64
// v2: software-pipelined phases + lgkm-only barriers + u/dt prefetch.
//
// Structure vs v1 (3455 us): the big gh = h(k) @ w_hh.T work (cols 32..159
// of each thread's 40-col gate slice) is computed in chunks DURING the
// wave0/1-only serial phases (head/theta/RK4/lift) instead of its own
// full-width phase; only the x-part (gi) of the gate dot stays on the
// critical path. Barriers are raw s_barrier + s_waitcnt lgkmcnt(0) (NO
// vmcnt drain), so out_ys/out_th stores and the next-step u/dt prefetch
// loads stay in flight across iterations. 5 barriers/iter (was 6 full
// __syncthreads, each of which drained vmcnt(0) = store-ack + load stall).

// NOTE: macro param must NOT be named `w` — (v).w would be captured.
#define DOT4(acc, v, arr, base)                                           \
  acc += (v).x * (arr)[(base)] + (v).y * (arr)[(base) + 1] +              \
         (v).z * (arr)[(base) + 2] + (v).w * (arr)[(base) + 3];

__device__ __forceinline__ float sigf(float x) {
  return 1.0f / (1.0f + __expf(-x));
}

__device__ __forceinline__ float tanh_fast(float x) {
  float ax = fabsf(x);
  float e = __expf(2.0f * ax);
  float r = 1.0f - 2.0f / (e + 1.0f);
  return copysignf(r, x);
}

// LDS-only producer->consumer barrier: drains lgkmcnt (LDS) but NOT vmcnt,
// so global stores and prefetch loads survive the barrier. Producer-side
// lgkmcnt(0) before s_barrier guarantees LDS writes are visible to other
// waves after it. asm memory clobbers pin LDS ops on their side.
#define BAR()                                            \
  do {                                                   \
    asm volatile("s_waitcnt lgkmcnt(0)" ::: "memory");   \
    __builtin_amdgcn_s_barrier();                        \
    asm volatile("" ::: "memory");                       \
  } while (0)

extern "C" __global__ __launch_bounds__(512, 2) void odernn_kernel(
    const float* __restrict__ y0, const float* __restrict__ u_seq,
    const float* __restrict__ dt_seq, const float* __restrict__ y_seq,
    const float* __restrict__ u2y, const float* __restrict__ lift_W,
    const float* __restrict__ lift_b, const float* __restrict__ w_ih,
    const float* __restrict__ w_hh, const float* __restrict__ b_ih,
    const float* __restrict__ b_hh, const float* __restrict__ head_W,
    const float* __restrict__ head_b, const int* __restrict__ tf_p,
    float* __restrict__ out_ys, float* __restrict__ out_th) {
  __shared__ __align__(16) float vecL[2][160];   // [x(32) | h(128)] per batch
  __shared__ __align__(16) float featL[2][48];   // [u(16) | y_in(32)] wave0-private
  __shared__ float gpart[4][2][4][128];          // q, bb, {R,Z,Nx,Nh}, j
  __shared__ float hpart[8][2][64];              // head partials
  __shared__ float thetaL[2][64];
  __shared__ float dtL[2];
  __shared__ float liftL[32 * 49];               // stride 49: conflict-free
  __shared__ float u2yL[16 * 32];

  const int t = threadIdx.x;
  const int b0 = blockIdx.x * 2;
  const int j = t & 127;   // hidden unit
  const int q = t >> 7;    // col-slice [40q, 40q+40)
  const int tfe = *tf_p;

  // ---- register-resident gate weights: rows j, j+128, j+256; cols 40q..40q+39
  // (cols < 32 are x-cols of w_ih, only q==0; cols >= 32 map to w_hh col-32)
  float wr[40], wz[40], wn[40];
  {
    const int jr = j, jz = j + 128, jn = j + 256;
#pragma unroll
    for (int cc = 0; cc < 40; ++cc) {
      int c = q * 40 + cc;
      if (c < 32) {
        wr[cc] = w_ih[jr * 32 + c];
        wz[cc] = w_ih[jz * 32 + c];
        wn[cc] = w_ih[jn * 32 + c];
      } else {
        wr[cc] = w_hh[jr * 128 + c - 32];
        wz[cc] = w_hh[jz * 128 + c - 32];
        wn[cc] = w_hh[jn * 128 + c - 32];
      }
    }
  }
  const int ho = t & 63;   // head output
  const int he = t >> 6;   // head k-slice [16he, 16he+16)
  float wh[16];
#pragma unroll
  for (int i = 0; i < 16; ++i) wh[i] = head_W[ho * 128 + he * 16 + i];

  float bR = 0, bZ = 0, bIn = 0, bHn = 0, hb = 0, lb = 0;
  if (t < 128) {
    bR = b_ih[j] + b_hh[j];
    bZ = b_ih[j + 128] + b_hh[j + 128];
    bIn = b_ih[j + 256];
    bHn = b_hh[j + 256];
    hb = head_b[ho];
  }
  if (t < 64) lb = lift_b[t & 31];

  for (int idx = t; idx < 32 * 48; idx += 512)
    liftL[(idx / 48) * 49 + (idx % 48)] = lift_W[idx];
  u2yL[t] = u2y[t];  // 512 elements, one per thread
  if (t < 128) {
    vecL[0][32 + j] = 0.0f;  // h0 = 0
    vecL[1][32 + j] = 0.0f;
  }

  float hreg[2] = {0.0f, 0.0f};
  float yreg = 0.0f;
  if (t < 64) yreg = y0[(b0 + (t >> 5)) * 32 + (t & 31)];

  __syncthreads();  // liftL/u2yL/vecL-h visible to all

  // ---- prologue: stage feat(0) + prefetch row 1 + lift x(0)  [wave 0 only]
  float upf = 0.0f, dtpf = 0.0f;
  if (t < 32) {
    const int bb = t >> 4, i = t & 15;
    featL[bb][i] = u_seq[((b0 + bb) * 1024 + 0) * 16 + i];
    upf = u_seq[((b0 + bb) * 1024 + 1) * 16 + i];
  }
  if (t >= 32 && t < 34) {
    const int bb = t - 32;
    dtL[bb] = dt_seq[(b0 + bb) * 1024 + 0];
    dtpf = dt_seq[(b0 + bb) * 1024 + 1];
  }
  if (t < 64) {
    const int bb = t >> 5, o = t & 31;
    featL[bb][16 + o] = yreg;  // k=0: no teacher forcing
    float a0 = lb, a1 = 0.f, a2 = 0.f, a3 = 0.f;
#pragma unroll
    for (int i = 0; i < 48; i += 4) {
      a0 += featL[bb][i] * liftL[o * 49 + i];
      a1 += featL[bb][i + 1] * liftL[o * 49 + i + 1];
      a2 += featL[bb][i + 2] * liftL[o * 49 + i + 2];
      a3 += featL[bb][i + 3] * liftL[o * 49 + i + 3];
    }
    float acc = (a0 + a1) + (a2 + a3);
    vecL[bb][o] = acc * sigf(acc);
  }
  // gh accumulators (gate partials over this thread's h-cols of h(k));
  // entering iter k they hold gh(h(k-1)); h(-1)=0 -> zeros.
  float gR[2] = {0.f, 0.f}, gZ[2] = {0.f, 0.f}, gNh[2] = {0.f, 0.f};
  int mtf = 1 % tfe;  // tracks (k+1) % tfe without a per-iter div
  __syncthreads();    // x(0)/feat(0) visible

  for (int k = 0; k < 1024; ++k) {
    // ---- P1: finish gate partials and publish.
    // q==0: x-part (32 cols) of R/Z/Nx on x(k), + its 8 h-cols (in gNh).
    // q>=1: last h-chunk (f4 window [7,10)) on h(k-1)=vecL h (P2 not run yet).
    if (q == 0) {
#pragma unroll
      for (int bb = 0; bb < 2; ++bb) {
        const float4* v4 = reinterpret_cast<const float4*>(&vecL[bb][0]);
        float aR = gR[bb], aZ = gZ[bb], aX = 0.f;
#pragma unroll
        for (int i = 0; i < 8; ++i) {
          float4 v = v4[i];
          DOT4(aR, v, wr, 4 * i)
          DOT4(aZ, v, wz, 4 * i)
          DOT4(aX, v, wn, 4 * i)
        }
        gpart[0][bb][0][j] = aR;
        gpart[0][bb][1][j] = aZ;
        gpart[0][bb][2][j] = aX;       // i_n x-part (kept separate: r*h_n)
        gpart[0][bb][3][j] = gNh[bb];  // h_n part (8 h-cols from P3)
      }
    } else {
#pragma unroll
      for (int bb = 0; bb < 2; ++bb) {
        const float4* v4 = reinterpret_cast<const float4*>(&vecL[bb][q * 40]);
        float aR = gR[bb], aZ = gZ[bb], aN = gNh[bb];
#pragma unroll
        for (int i = 7; i < 10; ++i) {
          float4 v = v4[i];
          DOT4(aR, v, wr, 4 * i)
          DOT4(aZ, v, wz, 4 * i)
          DOT4(aN, v, wn, 4 * i)
        }
        gpart[q][bb][0][j] = aR;
        gpart[q][bb][1][j] = aZ;
        gpart[q][bb][3][j] = aN;
      }
    }
    BAR();  // B1: gpart ready

    // ---- P2: GRU combine + h update (t<128)
    if (t < 128) {
#pragma unroll
      for (int bb = 0; bb < 2; ++bb) {
        float sR = bR, sZ = bZ, sNh = bHn;
#pragma unroll
        for (int qq = 0; qq < 4; ++qq) {
          sR += gpart[qq][bb][0][j];
          sZ += gpart[qq][bb][1][j];
          sNh += gpart[qq][bb][3][j];
        }
        float sNx = bIn + gpart[0][bb][2][j];
        float r = sigf(sR);
        float z = sigf(sZ);
        float n = tanh_fast(sNx + r * sNh);
        float hn = (1.0f - z) * n + z * hreg[bb];
        hreg[bb] = hn;
        vecL[bb][32 + j] = hn;
      }
    }
    BAR();  // B2: h(k) ready

    // ---- P3: head partials (all) + gh chunk A on h(k)
#pragma unroll
    for (int bb = 0; bb < 2; ++bb) {
      const float4* h4 =
          reinterpret_cast<const float4*>(&vecL[bb][32]) + he * 4;
      float a = 0.0f;
#pragma unroll
      for (int i = 0; i < 4; ++i) {
        float4 v = h4[i];
        DOT4(a, v, wh, 4 * i)
      }
      hpart[he][bb][ho] = a;
    }
    if (q == 0) {
      // q0's only h-cols: wr[32..40) <-> h[0..8)
#pragma unroll
      for (int bb = 0; bb < 2; ++bb) {
        const float4* v4 = reinterpret_cast<const float4*>(&vecL[bb][32]);
        float aR = 0.f, aZ = 0.f, aN = 0.f;
#pragma unroll
        for (int i = 0; i < 2; ++i) {
          float4 v = v4[i];
          DOT4(aR, v, wr, 32 + 4 * i)
          DOT4(aZ, v, wz, 32 + 4 * i)
          DOT4(aN, v, wn, 32 + 4 * i)
        }
        gR[bb] = aR; gZ[bb] = aZ; gNh[bb] = aN;
      }
    } else {
      // chunk A: f4 window [0,2)
#pragma unroll
      for (int bb = 0; bb < 2; ++bb) {
        const float4* v4 = reinterpret_cast<const float4*>(&vecL[bb][q * 40]);
        float aR = 0.f, aZ = 0.f, aN = 0.f;
#pragma unroll
        for (int i = 0; i < 2; ++i) {
          float4 v = v4[i];
          DOT4(aR, v, wr, 4 * i)
          DOT4(aZ, v, wz, 4 * i)
          DOT4(aN, v, wn, 4 * i)
        }
        gR[bb] = aR; gZ[bb] = aZ; gNh[bb] = aN;
      }
    }
    BAR();  // B3: hpart ready

    // ---- P4: theta (t<128) || gh chunk B (t>=128)
    if (t < 128) {
      const int bb = t >> 6, o = t & 63;
      float s = hb;
#pragma unroll
      for (int e = 0; e < 8; ++e) s += hpart[e][bb][o];
      float th = 0.001f + 1.999f * sigf(s);
      thetaL[bb][o] = th;
      out_th[(size_t)((b0 + bb) * 1024 + k) * 64 + o] = th;
    } else {
      // chunk B: f4 window [2,4)
#pragma unroll
      for (int bb = 0; bb < 2; ++bb) {
        const float4* v4 = reinterpret_cast<const float4*>(&vecL[bb][q * 40]);
        float aR = gR[bb], aZ = gZ[bb], aN = gNh[bb];
#pragma unroll
        for (int i = 2; i < 4; ++i) {
          float4 v = v4[i];
          DOT4(aR, v, wr, 4 * i)
          DOT4(aZ, v, wz, 4 * i)
          DOT4(aN, v, wn, 4 * i)
        }
        gR[bb] = aR; gZ[bb] = aZ; gNh[bb] = aN;
      }
    }
    BAR();  // B4: thetaL ready

    // ---- P5: gh chunk C (t>=128) || wave0: RK4 + stage(k+1) + prefetch + lift
    if (q >= 1) {
      // chunk C: f4 window [4,7)
#pragma unroll
      for (int bb = 0; bb < 2; ++bb) {
        const float4* v4 = reinterpret_cast<const float4*>(&vecL[bb][q * 40]);
        float aR = gR[bb], aZ = gZ[bb], aN = gNh[bb];
#pragma unroll
        for (int i = 4; i < 7; ++i) {
          float4 v = v4[i];
          DOT4(aR, v, wr, 4 * i)
          DOT4(aZ, v, wz, 4 * i)
          DOT4(aN, v, wn, 4 * i)
        }
        gR[bb] = aR; gZ[bb] = aZ; gNh[bb] = aN;
      }
    }
    if (t < 64) {
      const int bb = t >> 5, jj = t & 31;
      // jump (reads featL-u(k)) + RK4 (reads thetaL(k), dtL(k))
      float y = yreg;
#pragma unroll
      for (int i = 0; i < 16; ++i) y += featL[bb][i] * u2yL[i * 32 + jj];
      float a = thetaL[bb][jj];
      float b2 = thetaL[bb][32 + jj];
      float hdt = dtL[bb];
      float k1 = b2 - a * y;
      float k2 = b2 - a * (y + 0.5f * hdt * k1);
      float k3 = b2 - a * (y + 0.5f * hdt * k2);
      float k4 = b2 - a * (y + hdt * k3);
      y += hdt * (1.0f / 6.0f) * (k1 + 2.0f * k2 + 2.0f * k3 + k4);
      yreg = y;
      out_ys[(size_t)((b0 + bb) * 1024 + k) * 32 + jj] = y;
    }
    // stage step k+1 (wave0; consume prefetch regs, re-issue for k+2)
    if (t < 32) {
      const int bb = t >> 4, i = t & 15;
      featL[bb][i] = upf;
      const int kn = (k + 2 < 1024) ? k + 2 : 1023;
      upf = u_seq[((b0 + bb) * 1024 + kn) * 16 + i];
    }
    if (t >= 32 && t < 34) {
      const int bb = t - 32;
      dtL[bb] = dtpf;
      const int kn = (k + 2 < 1024) ? k + 2 : 1023;
      dtpf = dt_seq[(b0 + bb) * 1024 + kn];
    }
    if (t < 64) {
      const int bb = t >> 5, o = t & 31;
      float yin = yreg;
      if (mtf == 0)  // (k+1) % tfe == 0  (k+1 >= 1 always)
        yin = y_seq[(size_t)((b0 + bb) * 1024 + k) * 32 + o];
      featL[bb][16 + o] = yin;
      // lift(k+1): x = silu(feat @ lift_W.T + b)   [same wave: no barrier]
      float a0 = lb, a1 = 0.f, a2 = 0.f, a3 = 0.f;
#pragma unroll
      for (int i = 0; i < 48; i += 4) {
        a0 += featL[bb][i] * liftL[o * 49 + i];
        a1 += featL[bb][i + 1] * liftL[o * 49 + i + 1];
        a2 += featL[bb][i + 2] * liftL[o * 49 + i + 2];
        a3 += featL[bb][i + 3] * liftL[o * 49 + i + 3];
      }
      float acc = (a0 + a1) + (a2 + a3);
      vecL[bb][o] = acc * sigf(acc);
    }
    mtf = (mtf + 1 == tfe) ? 0 : mtf + 1;
    BAR();  // B5: x(k+1) ready; close iteration
  }
}

extern "C" void kernel_launch(void* const* d_in, const int* in_sizes, int n_in,
                              void* d_out, int out_size, void* d_ws,
                              size_t ws_size, hipStream_t stream) {
  (void)in_sizes; (void)n_in; (void)out_size; (void)d_ws; (void)ws_size;
  const float* y0     = (const float*)d_in[0];
  const float* u_seq  = (const float*)d_in[1];
  const float* dt_seq = (const float*)d_in[2];
  const float* y_seq  = (const float*)d_in[3];
  const float* u2y    = (const float*)d_in[4];
  const float* lift_W = (const float*)d_in[5];
  const float* lift_b = (const float*)d_in[6];
  const float* w_ih   = (const float*)d_in[7];
  const float* w_hh   = (const float*)d_in[8];
  const float* b_ih   = (const float*)d_in[9];
  const float* b_hh   = (const float*)d_in[10];
  const float* head_W = (const float*)d_in[11];
  const float* head_b = (const float*)d_in[12];
  const int*   tf_p   = (const int*)d_in[13];

  float* out_ys = (float*)d_out;
  float* out_th = out_ys + (size_t)512 * 1024 * 32;

  odernn_kernel<<<dim3(256), dim3(512), 0, stream>>>(
      y0, u_seq, dt_seq, y_seq, u2y, lift_W, lift_b, w_ih, w_hh, b_ih, b_hh,
      head_W, head_b, tf_p, out_ys, out_th);
}